// Round 2
// baseline (2537.573 us; speedup 1.0000x reference)
//
#include <hip/hip_runtime.h>

// ChebConv GNN: 6 layers x (K=5 Chebyshev) on 50000 nodes / 640000 edges, WIDTH=128.
// Strategy:
//  - Build CSR (grouped by dst) once per launch -> propagate is atomic-free, coalesced.
//  - prop_kernel computes out = scale * (L_hat @ xin) - sub  (fuses Cheb recurrence combine).
//  - gemm_kernel: fp32 vector-ALU tiled GEMM (no fp32 MFMA on CDNA4), 64-row tiles,
//    K-chunked LDS staging, 8x4 register blocking, fused bias/accum/ReLU.
//  - linear_kernel: wave-per-node dot with shuffle reduce.
// NOTE: harness delivers integer inputs as int32 — edge_index is const int* (NOT int64).

#define NN 50000
#define NE 640000
#define WID 128

// ---------------- preprocessing ----------------

__global__ __launch_bounds__(256) void degree_kernel(const int* __restrict__ ei,
                                                     int* __restrict__ deg, int E) {
  int e = blockIdx.x * 256 + threadIdx.x;
  if (e < E) {
    int d = ei[E + e];
    atomicAdd(&deg[d], 1);
  }
}

__global__ __launch_bounds__(256) void dinv_kernel(const int* __restrict__ deg,
                                                   float* __restrict__ dinv, int n) {
  int i = blockIdx.x * 256 + threadIdx.x;
  if (i < n) {
    float d = (float)deg[i];
    dinv[i] = d > 0.0f ? rsqrtf(d) : 0.0f;
  }
}

// Single-block exclusive scan of deg[0..n) -> row_start / fill_ptr; row_start[n]=total.
__global__ __launch_bounds__(1024) void scan_kernel(const int* __restrict__ deg,
                                                    int* __restrict__ row_start,
                                                    int* __restrict__ fill_ptr, int n) {
  __shared__ int wsum[16];
  int tid = threadIdx.x;
  int lane = tid & 63, wid = tid >> 6;
  int running = 0;
  for (int base = 0; base < n; base += 1024) {
    int i = base + tid;
    int cnt = (i < n) ? deg[i] : 0;
    int v = cnt;
#pragma unroll
    for (int off = 1; off < 64; off <<= 1) {
      int u = __shfl_up(v, off, 64);
      if (lane >= off) v += u;
    }
    if (lane == 63) wsum[wid] = v;
    __syncthreads();
    if (wid == 0) {
      int s = (lane < 16) ? wsum[lane] : 0;
#pragma unroll
      for (int off = 1; off < 16; off <<= 1) {
        int u = __shfl_up(s, off, 64);
        if (lane >= off) s += u;
      }
      if (lane < 16) wsum[lane] = s;
    }
    __syncthreads();
    int wexcl = (wid == 0) ? 0 : wsum[wid - 1];
    int total = wsum[15];
    int excl = running + wexcl + (v - cnt);
    if (i < n) { row_start[i] = excl; fill_ptr[i] = excl; }
    running += total;
    __syncthreads();
  }
  if (tid == 0) row_start[n] = running;
}

__global__ __launch_bounds__(256) void fill_kernel(const int* __restrict__ ei,
                                                   const float* __restrict__ dinv,
                                                   int* __restrict__ fill_ptr,
                                                   int* __restrict__ csr_src,
                                                   float* __restrict__ csr_norm, int E) {
  int e = blockIdx.x * 256 + threadIdx.x;
  if (e < E) {
    int s = ei[e];
    int d = ei[E + e];
    int pos = atomicAdd(&fill_ptr[d], 1);
    csr_src[pos] = s;
    csr_norm[pos] = -dinv[s] * dinv[d];
  }
}

// ---------------- propagate: out = scale * (L_hat @ xin) - sub ----------------
// 32 lanes per node (float4 per lane = 128 channels), 8 nodes per 256-thread block.

__global__ __launch_bounds__(256) void prop_kernel(float* __restrict__ out,
                                                   const float* __restrict__ xin,
                                                   const float* __restrict__ sub,
                                                   float scale,
                                                   const int* __restrict__ row_start,
                                                   const int* __restrict__ csr_src,
                                                   const float* __restrict__ csr_norm,
                                                   int n) {
  int node = blockIdx.x * 8 + (threadIdx.x >> 5);
  if (node >= n) return;
  int t = threadIdx.x & 31;
  int s = row_start[node], e = row_start[node + 1];
  float ax = 0.f, ay = 0.f, az = 0.f, aw = 0.f;
  for (int i = s; i < e; ++i) {
    int src = csr_src[i];
    float nrm = csr_norm[i];
    const float4 v = *(const float4*)(xin + (size_t)src * WID + t * 4);
    ax += nrm * v.x; ay += nrm * v.y; az += nrm * v.z; aw += nrm * v.w;
  }
  size_t o = (size_t)node * WID + t * 4;
  float4 r;
  r.x = scale * ax; r.y = scale * ay; r.z = scale * az; r.w = scale * aw;
  if (sub) {
    const float4 sv = *(const float4*)(sub + o);
    r.x -= sv.x; r.y -= sv.y; r.z -= sv.z; r.w -= sv.w;
  }
  *(float4*)(out + o) = r;
}

// ---------------- GEMM: C[M,128] (+)= A[M,128] @ W[128,128] (+bias) (ReLU) ----------------
// mode bit0 = accumulate into C, bit1 = ReLU. Tile: 64 rows x 128 cols per 256-thread block.
// K chunked by 64: LDS = As[64][72] (18.4KB, transposed+padded) + Ws[64][128] (32KB).

__global__ __launch_bounds__(256) void gemm_kernel(const float* __restrict__ A,
                                                   const float* __restrict__ W,
                                                   const float* __restrict__ bias,
                                                   float* __restrict__ C, int M, int mode) {
  __shared__ float As[64][72];   // [k_local][row], pad 64->72
  __shared__ float Ws[64][128];  // [k_local][col]
  int tid = threadIdx.x;
  int row_base = blockIdx.x * 64;

  int tx = tid & 31, ty = tid >> 5;     // col0 = tx*4 (128 cols), row0 = ty*8 (64 rows)
  int col0 = tx * 4, row0 = ty * 8;
  float acc[8][4];
#pragma unroll
  for (int r = 0; r < 8; ++r)
#pragma unroll
    for (int c = 0; c < 4; ++c) acc[r][c] = 0.f;

  int r_stage = tid & 63, c0_stage = tid >> 6;  // staging coords for A
  int grow_stage = row_base + r_stage;
  bool valid = grow_stage < M;
  const float4* Arow = (const float4*)(A + (size_t)grow_stage * WID);

  for (int kc = 0; kc < 2; ++kc) {
    // stage W chunk: 64x128 floats = 2048 float4
    {
      const float4* W4 = (const float4*)(W + (size_t)kc * 64 * WID);
      float4* s4 = (float4*)(&Ws[0][0]);
#pragma unroll
      for (int i = 0; i < 8; ++i) s4[tid + i * 256] = W4[tid + i * 256];
    }
    // stage A chunk transposed: local k = c4*4+j maps to global float4 col kc*16+c4
    {
#pragma unroll
      for (int j = 0; j < 4; ++j) {
        int c4 = c0_stage * 4 + j;  // 0..15 local float4 k-group
        float4 v = valid ? Arow[kc * 16 + c4] : make_float4(0.f, 0.f, 0.f, 0.f);
        int k = c4 * 4;
        As[k + 0][r_stage] = v.x;
        As[k + 1][r_stage] = v.y;
        As[k + 2][r_stage] = v.z;
        As[k + 3][r_stage] = v.w;
      }
    }
    __syncthreads();

#pragma unroll 4
    for (int k = 0; k < 64; ++k) {
      const float4 w = *(const float4*)(&Ws[k][col0]);
      const float4 a0 = *(const float4*)(&As[k][row0]);
      const float4 a1 = *(const float4*)(&As[k][row0 + 4]);
      float ar[8] = {a0.x, a0.y, a0.z, a0.w, a1.x, a1.y, a1.z, a1.w};
      float wr[4] = {w.x, w.y, w.z, w.w};
#pragma unroll
      for (int r = 0; r < 8; ++r)
#pragma unroll
        for (int c = 0; c < 4; ++c) acc[r][c] += ar[r] * wr[c];
    }
    __syncthreads();
  }

  bool accum = (mode & 1) != 0;
  bool relu = (mode & 2) != 0;
  float4 bv = make_float4(0.f, 0.f, 0.f, 0.f);
  if (bias) bv = *(const float4*)(bias + col0);
#pragma unroll
  for (int r = 0; r < 8; ++r) {
    int grow = row_base + row0 + r;
    if (grow < M) {
      float* Cp = C + (size_t)grow * WID + col0;
      float4 v = make_float4(acc[r][0] + bv.x, acc[r][1] + bv.y,
                             acc[r][2] + bv.z, acc[r][3] + bv.w);
      if (accum) {
        const float4 o = *(const float4*)Cp;
        v.x += o.x; v.y += o.y; v.z += o.z; v.w += o.w;
      }
      if (relu) {
        v.x = fmaxf(v.x, 0.f); v.y = fmaxf(v.y, 0.f);
        v.z = fmaxf(v.z, 0.f); v.w = fmaxf(v.w, 0.f);
      }
      *(float4*)Cp = v;
    }
  }
}

// ---------------- final Linear(128 -> 1) ----------------

__global__ __launch_bounds__(256) void linear_kernel(const float* __restrict__ h,
                                                     const float* __restrict__ w,
                                                     const float* __restrict__ b,
                                                     float* __restrict__ y, int n) {
  int node = blockIdx.x * 4 + (threadIdx.x >> 6);
  int lane = threadIdx.x & 63;
  if (node >= n) return;
  const float* hr = h + (size_t)node * WID;
  float v = hr[lane] * w[lane] + hr[lane + 64] * w[lane + 64];
#pragma unroll
  for (int off = 32; off > 0; off >>= 1) v += __shfl_down(v, off, 64);
  if (lane == 0) y[node] = v + b[0];
}

// ---------------- host orchestration ----------------

extern "C" void kernel_launch(void* const* d_in, const int* in_sizes, int n_in,
                              void* d_out, int out_size, void* d_ws, size_t ws_size,
                              hipStream_t stream) {
  const float* x = (const float*)d_in[0];
  const int* ei = (const int*)d_in[1];          // int32 per harness contract
  const float* conv_w = (const float*)d_in[2];  // [6][5][128][128]
  const float* conv_b = (const float*)d_in[3];  // [6][128]
  const float* lin_w = (const float*)d_in[4];   // [128]
  const float* lin_b = (const float*)d_in[5];   // [1]

  const int N = NN, E = NE, C = WID, K = 5, L = 6;

  char* ws = (char*)d_ws;
  size_t off = 0;
  auto alloc = [&](size_t bytes) -> void* {
    void* p = ws + off;
    off = (off + bytes + 255) & ~(size_t)255;
    return p;
  };
  int* deg = (int*)alloc((size_t)N * 4);
  float* dinv = (float*)alloc((size_t)N * 4);
  int* row_start = (int*)alloc((size_t)(N + 1) * 4);
  int* fill_ptr = (int*)alloc((size_t)N * 4);
  int* csr_src = (int*)alloc((size_t)E * 4);
  float* csr_norm = (float*)alloc((size_t)E * 4);
  float* bufA = (float*)alloc((size_t)N * C * 4);
  float* bufB = (float*)alloc((size_t)N * C * 4);
  float* bufC = (float*)alloc((size_t)N * C * 4);
  float* H0 = (float*)alloc((size_t)N * C * 4);
  float* H1 = (float*)alloc((size_t)N * C * 4);

  // preprocessing
  hipMemsetAsync(deg, 0, (size_t)N * 4, stream);
  degree_kernel<<<(E + 255) / 256, 256, 0, stream>>>(ei, deg, E);
  dinv_kernel<<<(N + 255) / 256, 256, 0, stream>>>(deg, dinv, N);
  scan_kernel<<<1, 1024, 0, stream>>>(deg, row_start, fill_ptr, N);
  fill_kernel<<<(E + 255) / 256, 256, 0, stream>>>(ei, dinv, fill_ptr, csr_src, csr_norm, E);

  const int gg = (N + 63) / 64;     // GEMM grid
  const int pg = (N + 7) / 8;       // prop grid
  const float* h = x;
  float* Hb[2] = {H0, H1};

  for (int l = 0; l < L; ++l) {
    float* out = Hb[l & 1];
    const float* Wl = conv_w + (size_t)l * K * C * C;
    const float* bl = conv_b + (size_t)l * C;
    int relu_flag = (l < L - 1) ? 2 : 0;

    // k=0: out = h @ W0 + b  (write mode)
    gemm_kernel<<<gg, 256, 0, stream>>>(h, Wl + 0 * C * C, bl, out, N, 0);
    // T1 = L h
    prop_kernel<<<pg, 256, 0, stream>>>(bufA, h, nullptr, 1.0f, row_start, csr_src, csr_norm, N);
    gemm_kernel<<<gg, 256, 0, stream>>>(bufA, Wl + 1 * C * C, nullptr, out, N, 1);
    // T2 = 2 L T1 - T0
    prop_kernel<<<pg, 256, 0, stream>>>(bufB, bufA, h, 2.0f, row_start, csr_src, csr_norm, N);
    gemm_kernel<<<gg, 256, 0, stream>>>(bufB, Wl + 2 * C * C, nullptr, out, N, 1);
    // T3 = 2 L T2 - T1
    prop_kernel<<<pg, 256, 0, stream>>>(bufC, bufB, bufA, 2.0f, row_start, csr_src, csr_norm, N);
    gemm_kernel<<<gg, 256, 0, stream>>>(bufC, Wl + 3 * C * C, nullptr, out, N, 1);
    // T4 = 2 L T3 - T2  (bufA is dead, reuse)
    prop_kernel<<<pg, 256, 0, stream>>>(bufA, bufC, bufB, 2.0f, row_start, csr_src, csr_norm, N);
    gemm_kernel<<<gg, 256, 0, stream>>>(bufA, Wl + 4 * C * C, nullptr, out, N, 1 | relu_flag);

    h = out;
  }

  linear_kernel<<<(N + 3) / 4, 256, 0, stream>>>(h, lin_w, lin_b, (float*)d_out, N);
}

// Round 3
// 1629.066 us; speedup vs baseline: 1.5577x; 1.5577x over previous
//
#include <hip/hip_runtime.h>

// ChebConv GNN: 6 layers x (K=5 Chebyshev), 50000 nodes / 640000 edges, WIDTH=128.
//  - CSR build once per launch -> atomic-free coalesced propagate.
//  - prop_kernel: fp32 recurrence out = scale*(L_hat@xin) - sub, 4x-unrolled gather,
//    also emits bf16 copy of the result (GEMM A-operand).
//  - cheb_gemm: ONE fused GEMM per layer: H = [T0|T1|T2|T3|T4](bf16, N x 640) @ Wt + b,
//    bf16 MFMA 16x16x32, fp32 accum, fused bias/ReLU, emits bf16 T0 for next layer.
//  - weights pre-transposed to Wt[l][col][k] bf16 once per launch.

#define NN 50000
#define NE 640000
#define WID 128

typedef __attribute__((ext_vector_type(8))) short bf16x8;
typedef __attribute__((ext_vector_type(4))) float f32x4;

__device__ __forceinline__ unsigned short f2bf(float f) {
  union { float f; unsigned int u; } v; v.f = f;
  unsigned int r = v.u + 0x7FFF + ((v.u >> 16) & 1);  // RNE
  return (unsigned short)(r >> 16);
}

// ---------------- preprocessing ----------------

__global__ __launch_bounds__(256) void degree_kernel(const int* __restrict__ ei,
                                                     int* __restrict__ deg, int E) {
  int e = blockIdx.x * 256 + threadIdx.x;
  if (e < E) atomicAdd(&deg[ei[E + e]], 1);
}

__global__ __launch_bounds__(256) void dinv_kernel(const int* __restrict__ deg,
                                                   float* __restrict__ dinv, int n) {
  int i = blockIdx.x * 256 + threadIdx.x;
  if (i < n) {
    float d = (float)deg[i];
    dinv[i] = d > 0.0f ? rsqrtf(d) : 0.0f;
  }
}

__global__ __launch_bounds__(1024) void scan_kernel(const int* __restrict__ deg,
                                                    int* __restrict__ row_start,
                                                    int* __restrict__ fill_ptr, int n) {
  __shared__ int wsum[16];
  int tid = threadIdx.x;
  int lane = tid & 63, wid = tid >> 6;
  int running = 0;
  for (int base = 0; base < n; base += 1024) {
    int i = base + tid;
    int cnt = (i < n) ? deg[i] : 0;
    int v = cnt;
#pragma unroll
    for (int off = 1; off < 64; off <<= 1) {
      int u = __shfl_up(v, off, 64);
      if (lane >= off) v += u;
    }
    if (lane == 63) wsum[wid] = v;
    __syncthreads();
    if (wid == 0) {
      int s = (lane < 16) ? wsum[lane] : 0;
#pragma unroll
      for (int off = 1; off < 16; off <<= 1) {
        int u = __shfl_up(s, off, 64);
        if (lane >= off) s += u;
      }
      if (lane < 16) wsum[lane] = s;
    }
    __syncthreads();
    int wexcl = (wid == 0) ? 0 : wsum[wid - 1];
    int total = wsum[15];
    int excl = running + wexcl + (v - cnt);
    if (i < n) { row_start[i] = excl; fill_ptr[i] = excl; }
    running += total;
    __syncthreads();
  }
  if (tid == 0) row_start[n] = running;
}

__global__ __launch_bounds__(256) void fill_kernel(const int* __restrict__ ei,
                                                   const float* __restrict__ dinv,
                                                   int* __restrict__ fill_ptr,
                                                   int* __restrict__ csr_src,
                                                   float* __restrict__ csr_norm, int E) {
  int e = blockIdx.x * 256 + threadIdx.x;
  if (e < E) {
    int s = ei[e];
    int d = ei[E + e];
    int pos = atomicAdd(&fill_ptr[d], 1);
    csr_src[pos] = s;
    csr_norm[pos] = -dinv[s] * dinv[d];
  }
}

// x fp32 -> bf16 (T0 of layer 0)
__global__ __launch_bounds__(256) void cvt_x_kernel(const float* __restrict__ x,
                                                    unsigned short* __restrict__ o, int n) {
  int i = blockIdx.x * 256 + threadIdx.x;
  if (i < n) o[i] = f2bf(x[i]);
}

// conv_w [6][5][128][128] fp32 -> Wt [6][128 cols][640 k] bf16   (k = kk*128 + m)
__global__ __launch_bounds__(256) void cvt_w_kernel(const float* __restrict__ w,
                                                    unsigned short* __restrict__ wt, int n) {
  int i = blockIdx.x * 256 + threadIdx.x;
  if (i < n) {
    int l = i / (WID * 640);
    int r = i % (WID * 640);
    int col = r / 640;
    int k = r % 640;
    int kk = k >> 7, m = k & 127;
    wt[i] = f2bf(w[(((size_t)l * 5 + kk) * WID + m) * WID + col]);
  }
}

// ---------------- propagate: out = scale * (L_hat @ xin) - sub ; bf16 copy ----------------
// out==sub is allowed (same-thread same-index read-then-write).

__global__ __launch_bounds__(256) void prop_kernel(float* out,
                                                   unsigned short* __restrict__ bf_out,
                                                   const float* __restrict__ xin,
                                                   const float* sub,
                                                   float scale,
                                                   const int* __restrict__ row_start,
                                                   const int* __restrict__ csr_src,
                                                   const float* __restrict__ csr_norm,
                                                   int n) {
  int node = blockIdx.x * 8 + (threadIdx.x >> 5);
  if (node >= n) return;
  int t = threadIdx.x & 31;
  int s = row_start[node], e = row_start[node + 1];
  float ax = 0.f, ay = 0.f, az = 0.f, aw = 0.f;
  int i = s;
  for (; i + 4 <= e; i += 4) {
    int s0 = csr_src[i], s1 = csr_src[i + 1], s2 = csr_src[i + 2], s3 = csr_src[i + 3];
    float n0 = csr_norm[i], n1 = csr_norm[i + 1], n2 = csr_norm[i + 2], n3 = csr_norm[i + 3];
    const float4 v0 = *(const float4*)(xin + (size_t)s0 * WID + t * 4);
    const float4 v1 = *(const float4*)(xin + (size_t)s1 * WID + t * 4);
    const float4 v2 = *(const float4*)(xin + (size_t)s2 * WID + t * 4);
    const float4 v3 = *(const float4*)(xin + (size_t)s3 * WID + t * 4);
    ax += n0 * v0.x + n1 * v1.x + n2 * v2.x + n3 * v3.x;
    ay += n0 * v0.y + n1 * v1.y + n2 * v2.y + n3 * v3.y;
    az += n0 * v0.z + n1 * v1.z + n2 * v2.z + n3 * v3.z;
    aw += n0 * v0.w + n1 * v1.w + n2 * v2.w + n3 * v3.w;
  }
  for (; i < e; ++i) {
    int src = csr_src[i];
    float nrm = csr_norm[i];
    const float4 v = *(const float4*)(xin + (size_t)src * WID + t * 4);
    ax += nrm * v.x; ay += nrm * v.y; az += nrm * v.z; aw += nrm * v.w;
  }
  size_t o = (size_t)node * WID + t * 4;
  float4 r;
  r.x = scale * ax; r.y = scale * ay; r.z = scale * az; r.w = scale * aw;
  if (sub) {
    const float4 sv = *(const float4*)(sub + o);
    r.x -= sv.x; r.y -= sv.y; r.z -= sv.z; r.w -= sv.w;
  }
  *(float4*)(out + o) = r;
  *(ushort4*)(bf_out + o) = make_ushort4(f2bf(r.x), f2bf(r.y), f2bf(r.z), f2bf(r.w));
}

// ---------------- fused layer GEMM: H[N,128] = A[N,640](bf16) @ W[640,128] + b ----------------
// A given as 5 chunk pointers (each N x 128 bf16). Wt is [128 cols][640 k] bf16.
// Block: 256 thr, 128 rows x 128 cols. MFMA 16x16x32 bf16. Wave w: rows w*32..w*32+31.

__global__ __launch_bounds__(256) void cheb_gemm(
    const unsigned short* __restrict__ T0, const unsigned short* __restrict__ T1,
    const unsigned short* __restrict__ T2, const unsigned short* __restrict__ T3,
    const unsigned short* __restrict__ T4,
    const unsigned short* __restrict__ Wt,
    const float* __restrict__ bias, float* __restrict__ H,
    unsigned short* __restrict__ T0next, int M, int relu) {
  __shared__ unsigned short As[128][40];  // [row][k 0..31], pad to 40 (80B rows)
  __shared__ unsigned short Bs[128][40];  // [col][k 0..31]
  const unsigned short* chunks[5] = {T0, T1, T2, T3, T4};
  int tid = threadIdx.x;
  int rowBase = blockIdx.x * 128;
  int wave = tid >> 6, lane = tid & 63;
  int lrow = lane & 15, quad = lane >> 4;
  int k0 = quad * 8;

  f32x4 acc[2][8];
#pragma unroll
  for (int a = 0; a < 2; ++a)
#pragma unroll
    for (int b = 0; b < 8; ++b) acc[a][b] = (f32x4){0.f, 0.f, 0.f, 0.f};

  int r_st = tid >> 1;                // 0..127 staging row/col
  int hh = (tid & 1) * 16;            // 16-bf16 half
  int grow_st = rowBase + r_st;
  bool aval = grow_st < M;
  const int4 zero4 = {0, 0, 0, 0};

  for (int kc = 0; kc < 20; ++kc) {
    // stage A (rows) from chunk kc/4, k-offset (kc%4)*32
    if (aval) {
      const unsigned short* ap = chunks[kc >> 2] + ((size_t)grow_st * WID + (kc & 3) * 32 + hh);
      *(int4*)(&As[r_st][hh]) = *(const int4*)ap;
      *(int4*)(&As[r_st][hh + 8]) = *(const int4*)(ap + 8);
    } else {
      *(int4*)(&As[r_st][hh]) = zero4;
      *(int4*)(&As[r_st][hh + 8]) = zero4;
    }
    // stage B (cols): Wt[col][kc*32 ..]
    {
      const unsigned short* bp = Wt + ((size_t)r_st * 640 + kc * 32 + hh);
      *(int4*)(&Bs[r_st][hh]) = *(const int4*)bp;
      *(int4*)(&Bs[r_st][hh + 8]) = *(const int4*)(bp + 8);
    }
    __syncthreads();

    bf16x8 a0 = *(bf16x8*)(&As[wave * 32 + lrow][k0]);
    bf16x8 a1 = *(bf16x8*)(&As[wave * 32 + 16 + lrow][k0]);
#pragma unroll
    for (int ct = 0; ct < 8; ++ct) {
      bf16x8 b = *(bf16x8*)(&Bs[ct * 16 + lrow][k0]);
      acc[0][ct] = __builtin_amdgcn_mfma_f32_16x16x32_bf16(a0, b, acc[0][ct], 0, 0, 0);
      acc[1][ct] = __builtin_amdgcn_mfma_f32_16x16x32_bf16(a1, b, acc[1][ct], 0, 0, 0);
    }
    __syncthreads();
  }

  // epilogue: C/D layout col=lane&15, row=quad*4+reg
#pragma unroll
  for (int rt = 0; rt < 2; ++rt) {
    int grow0 = rowBase + wave * 32 + rt * 16 + quad * 4;
#pragma unroll
    for (int ct = 0; ct < 8; ++ct) {
      int gcol = ct * 16 + lrow;
      float bv = bias[gcol];
#pragma unroll
      for (int reg = 0; reg < 4; ++reg) {
        int grow = grow0 + reg;
        if (grow < M) {
          float v = acc[rt][ct][reg] + bv;
          if (relu) v = fmaxf(v, 0.f);
          H[(size_t)grow * WID + gcol] = v;
          if (T0next) T0next[(size_t)grow * WID + gcol] = f2bf(v);
        }
      }
    }
  }
}

// ---------------- final Linear(128 -> 1) ----------------

__global__ __launch_bounds__(256) void linear_kernel(const float* __restrict__ h,
                                                     const float* __restrict__ w,
                                                     const float* __restrict__ b,
                                                     float* __restrict__ y, int n) {
  int node = blockIdx.x * 4 + (threadIdx.x >> 6);
  int lane = threadIdx.x & 63;
  if (node >= n) return;
  const float* hr = h + (size_t)node * WID;
  float v = hr[lane] * w[lane] + hr[lane + 64] * w[lane + 64];
#pragma unroll
  for (int off = 32; off > 0; off >>= 1) v += __shfl_down(v, off, 64);
  if (lane == 0) y[node] = v + b[0];
}

// ---------------- host orchestration ----------------

extern "C" void kernel_launch(void* const* d_in, const int* in_sizes, int n_in,
                              void* d_out, int out_size, void* d_ws, size_t ws_size,
                              hipStream_t stream) {
  const float* x = (const float*)d_in[0];
  const int* ei = (const int*)d_in[1];          // int32 per harness contract
  const float* conv_w = (const float*)d_in[2];  // [6][5][128][128]
  const float* conv_b = (const float*)d_in[3];  // [6][128]
  const float* lin_w = (const float*)d_in[4];   // [128]
  const float* lin_b = (const float*)d_in[5];   // [1]

  const int N = NN, E = NE, C = WID, L = 6;

  char* ws = (char*)d_ws;
  size_t off = 0;
  auto alloc = [&](size_t bytes) -> void* {
    void* p = ws + off;
    off = (off + bytes + 255) & ~(size_t)255;
    return p;
  };
  int* deg = (int*)alloc((size_t)N * 4);
  float* dinv = (float*)alloc((size_t)N * 4);
  int* row_start = (int*)alloc((size_t)(N + 1) * 4);
  int* fill_ptr = (int*)alloc((size_t)N * 4);
  int* csr_src = (int*)alloc((size_t)E * 4);
  float* csr_norm = (float*)alloc((size_t)E * 4);
  float* bufA = (float*)alloc((size_t)N * C * 4);   // fp32 rotating T
  float* bufB = (float*)alloc((size_t)N * C * 4);
  float* H = (float*)alloc((size_t)N * C * 4);      // fp32 layer output
  unsigned short* T0a = (unsigned short*)alloc((size_t)N * C * 2);
  unsigned short* T0b = (unsigned short*)alloc((size_t)N * C * 2);
  unsigned short* T1b = (unsigned short*)alloc((size_t)N * C * 2);
  unsigned short* T2b = (unsigned short*)alloc((size_t)N * C * 2);
  unsigned short* T3b = (unsigned short*)alloc((size_t)N * C * 2);
  unsigned short* T4b = (unsigned short*)alloc((size_t)N * C * 2);
  unsigned short* Wt = (unsigned short*)alloc((size_t)L * C * 640 * 2);

  // preprocessing
  hipMemsetAsync(deg, 0, (size_t)N * 4, stream);
  degree_kernel<<<(E + 255) / 256, 256, 0, stream>>>(ei, deg, E);
  dinv_kernel<<<(N + 255) / 256, 256, 0, stream>>>(deg, dinv, N);
  scan_kernel<<<1, 1024, 0, stream>>>(deg, row_start, fill_ptr, N);
  fill_kernel<<<(E + 255) / 256, 256, 0, stream>>>(ei, dinv, fill_ptr, csr_src, csr_norm, E);
  cvt_x_kernel<<<(N * C + 255) / 256, 256, 0, stream>>>(x, T0a, N * C);
  cvt_w_kernel<<<(L * C * 640 + 255) / 256, 256, 0, stream>>>(conv_w, Wt, L * C * 640);

  const int pg = (N + 7) / 8;        // prop grid
  const int gg = (N + 127) / 128;    // gemm grid

  for (int l = 0; l < L; ++l) {
    const float* hf = (l == 0) ? x : H;
    const unsigned short* T0c = (l & 1) ? T0b : T0a;
    unsigned short* T0n = (l < L - 1) ? ((l & 1) ? T0a : T0b) : nullptr;

    // T1 = L h
    prop_kernel<<<pg, 256, 0, stream>>>(bufA, T1b, hf, nullptr, 1.0f,
                                        row_start, csr_src, csr_norm, N);
    // T2 = 2 L T1 - T0
    prop_kernel<<<pg, 256, 0, stream>>>(bufB, T2b, bufA, hf, 2.0f,
                                        row_start, csr_src, csr_norm, N);
    // T3 = 2 L T2 - T1   (in-place over bufA)
    prop_kernel<<<pg, 256, 0, stream>>>(bufA, T3b, bufB, bufA, 2.0f,
                                        row_start, csr_src, csr_norm, N);
    // T4 = 2 L T3 - T2   (in-place over bufB)
    prop_kernel<<<pg, 256, 0, stream>>>(bufB, T4b, bufA, bufB, 2.0f,
                                        row_start, csr_src, csr_norm, N);
    // fused GEMM over K=640 + bias (+ReLU) -> H fp32 (+ bf16 T0 for next layer)
    cheb_gemm<<<gg, 256, 0, stream>>>(T0c, T1b, T2b, T3b, T4b,
                                      Wt + (size_t)l * C * 640, conv_b + (size_t)l * C,
                                      H, T0n, N, (l < L - 1) ? 1 : 0);
  }

  linear_kernel<<<(N + 3) / 4, 256, 0, stream>>>(H, lin_w, lin_b, (float*)d_out, N);
}

// Round 4
// 1071.581 us; speedup vs baseline: 2.3681x; 1.5202x over previous
//
#include <hip/hip_runtime.h>

// ChebConv GNN: 6 layers x (K=5 Chebyshev), 50000 nodes / 640000 edges, WIDTH=128.
//  - CSR (packed int2 {src,norm}) built once per launch -> atomic-free coalesced propagate.
//  - All Chebyshev T_k stored bf16; prop gathers bf16, accumulates fp32, writes bf16.
//  - cheb_gemm: ONE fused GEMM per layer: H = [T0..T4](bf16, N x 640) @ Wt + b,
//    bf16 MFMA 16x16x32, fp32 accum, fused bias/ReLU, writes bf16 H (= next T0);
//    final layer also writes fp32 H for the linear head.

#define NN 50000
#define NE 640000
#define WID 128

typedef __attribute__((ext_vector_type(8))) short bf16x8;
typedef __attribute__((ext_vector_type(4))) float f32x4;

__device__ __forceinline__ unsigned short f2bf(float f) {
  union { float f; unsigned int u; } v; v.f = f;
  unsigned int r = v.u + 0x7FFF + ((v.u >> 16) & 1);  // RNE
  return (unsigned short)(r >> 16);
}
__device__ __forceinline__ float bflo(unsigned int u) {
  return __uint_as_float(u << 16);
}
__device__ __forceinline__ float bfhi(unsigned int u) {
  return __uint_as_float(u & 0xffff0000u);
}

// ---------------- preprocessing ----------------

__global__ __launch_bounds__(256) void degree_kernel(const int* __restrict__ ei,
                                                     int* __restrict__ deg, int E) {
  int e = blockIdx.x * 256 + threadIdx.x;
  if (e < E) atomicAdd(&deg[ei[E + e]], 1);
}

__global__ __launch_bounds__(256) void dinv_kernel(const int* __restrict__ deg,
                                                   float* __restrict__ dinv, int n) {
  int i = blockIdx.x * 256 + threadIdx.x;
  if (i < n) {
    float d = (float)deg[i];
    dinv[i] = d > 0.0f ? rsqrtf(d) : 0.0f;
  }
}

__global__ __launch_bounds__(1024) void scan_kernel(const int* __restrict__ deg,
                                                    int* __restrict__ row_start,
                                                    int* __restrict__ fill_ptr, int n) {
  __shared__ int wsum[16];
  int tid = threadIdx.x;
  int lane = tid & 63, wid = tid >> 6;
  int running = 0;
  for (int base = 0; base < n; base += 1024) {
    int i = base + tid;
    int cnt = (i < n) ? deg[i] : 0;
    int v = cnt;
#pragma unroll
    for (int off = 1; off < 64; off <<= 1) {
      int u = __shfl_up(v, off, 64);
      if (lane >= off) v += u;
    }
    if (lane == 63) wsum[wid] = v;
    __syncthreads();
    if (wid == 0) {
      int s = (lane < 16) ? wsum[lane] : 0;
#pragma unroll
      for (int off = 1; off < 16; off <<= 1) {
        int u = __shfl_up(s, off, 64);
        if (lane >= off) s += u;
      }
      if (lane < 16) wsum[lane] = s;
    }
    __syncthreads();
    int wexcl = (wid == 0) ? 0 : wsum[wid - 1];
    int total = wsum[15];
    int excl = running + wexcl + (v - cnt);
    if (i < n) { row_start[i] = excl; fill_ptr[i] = excl; }
    running += total;
    __syncthreads();
  }
  if (tid == 0) row_start[n] = running;
}

__global__ __launch_bounds__(256) void fill_kernel(const int* __restrict__ ei,
                                                   const float* __restrict__ dinv,
                                                   int* __restrict__ fill_ptr,
                                                   int2* __restrict__ csr, int E) {
  int e = blockIdx.x * 256 + threadIdx.x;
  if (e < E) {
    int s = ei[e];
    int d = ei[E + e];
    int pos = atomicAdd(&fill_ptr[d], 1);
    csr[pos] = make_int2(s, __float_as_int(-dinv[s] * dinv[d]));
  }
}

// x fp32 -> bf16 (T0 of layer 0)
__global__ __launch_bounds__(256) void cvt_x_kernel(const float* __restrict__ x,
                                                    unsigned short* __restrict__ o, int n) {
  int i = blockIdx.x * 256 + threadIdx.x;
  if (i < n) o[i] = f2bf(x[i]);
}

// conv_w [6][5][128][128] fp32 -> Wt [6][128 cols][640 k] bf16   (k = kk*128 + m)
__global__ __launch_bounds__(256) void cvt_w_kernel(const float* __restrict__ w,
                                                    unsigned short* __restrict__ wt, int n) {
  int i = blockIdx.x * 256 + threadIdx.x;
  if (i < n) {
    int l = i / (WID * 640);
    int r = i % (WID * 640);
    int col = r / 640;
    int k = r % 640;
    int kk = k >> 7, m = k & 127;
    wt[i] = f2bf(w[(((size_t)l * 5 + kk) * WID + m) * WID + col]);
  }
}

// ---------------- propagate: out(bf16) = scale * (L_hat @ xin(bf16)) - sub(bf16) ----------------
// 32 lanes per node, lane handles 4 channels (8B = uint2 per gather). fp32 accumulate.

__global__ __launch_bounds__(256) void prop_kernel(unsigned short* __restrict__ out,
                                                   const unsigned short* __restrict__ xin,
                                                   const unsigned short* __restrict__ sub,
                                                   float scale,
                                                   const int* __restrict__ row_start,
                                                   const int2* __restrict__ csr,
                                                   int n) {
  int node = blockIdx.x * 8 + (threadIdx.x >> 5);
  if (node >= n) return;
  int t = threadIdx.x & 31;
  int s = row_start[node], e = row_start[node + 1];
  float a0 = 0.f, a1 = 0.f, a2 = 0.f, a3 = 0.f;
  int i = s;
  for (; i + 4 <= e; i += 4) {
    int2 e0 = csr[i], e1 = csr[i + 1], e2 = csr[i + 2], e3 = csr[i + 3];
    const uint2 v0 = *(const uint2*)(xin + (size_t)e0.x * WID + t * 4);
    const uint2 v1 = *(const uint2*)(xin + (size_t)e1.x * WID + t * 4);
    const uint2 v2 = *(const uint2*)(xin + (size_t)e2.x * WID + t * 4);
    const uint2 v3 = *(const uint2*)(xin + (size_t)e3.x * WID + t * 4);
    float n0 = __int_as_float(e0.y), n1 = __int_as_float(e1.y);
    float n2 = __int_as_float(e2.y), n3 = __int_as_float(e3.y);
    a0 += n0 * bflo(v0.x) + n1 * bflo(v1.x) + n2 * bflo(v2.x) + n3 * bflo(v3.x);
    a1 += n0 * bfhi(v0.x) + n1 * bfhi(v1.x) + n2 * bfhi(v2.x) + n3 * bfhi(v3.x);
    a2 += n0 * bflo(v0.y) + n1 * bflo(v1.y) + n2 * bflo(v2.y) + n3 * bflo(v3.y);
    a3 += n0 * bfhi(v0.y) + n1 * bfhi(v1.y) + n2 * bfhi(v2.y) + n3 * bfhi(v3.y);
  }
  for (; i < e; ++i) {
    int2 ee = csr[i];
    float nrm = __int_as_float(ee.y);
    const uint2 v = *(const uint2*)(xin + (size_t)ee.x * WID + t * 4);
    a0 += nrm * bflo(v.x); a1 += nrm * bfhi(v.x);
    a2 += nrm * bflo(v.y); a3 += nrm * bfhi(v.y);
  }
  size_t o = (size_t)node * WID + t * 4;
  float r0 = scale * a0, r1 = scale * a1, r2 = scale * a2, r3 = scale * a3;
  if (sub) {
    const uint2 sv = *(const uint2*)(sub + o);
    r0 -= bflo(sv.x); r1 -= bfhi(sv.x);
    r2 -= bflo(sv.y); r3 -= bfhi(sv.y);
  }
  *(ushort4*)(out + o) = make_ushort4(f2bf(r0), f2bf(r1), f2bf(r2), f2bf(r3));
}

// ---------------- fused layer GEMM: H[N,128] = A[N,640](bf16) @ W[640,128] + b ----------------
// A given as 5 chunk pointers (each N x 128 bf16). Wt is [128 cols][640 k] bf16.
// Block: 256 thr, 128 rows x 128 cols. MFMA 16x16x32 bf16. Writes bf16 Hb (= next T0);
// optionally fp32 Hf (final layer, for the linear head).

__global__ __launch_bounds__(256) void cheb_gemm(
    const unsigned short* __restrict__ T0, const unsigned short* __restrict__ T1,
    const unsigned short* __restrict__ T2, const unsigned short* __restrict__ T3,
    const unsigned short* __restrict__ T4,
    const unsigned short* __restrict__ Wt,
    const float* __restrict__ bias,
    unsigned short* __restrict__ Hb, float* __restrict__ Hf, int M, int relu) {
  __shared__ unsigned short As[128][40];  // [row][k 0..31], pad to 40
  __shared__ unsigned short Bs[128][40];  // [col][k 0..31]
  const unsigned short* chunks[5] = {T0, T1, T2, T3, T4};
  int tid = threadIdx.x;
  int rowBase = blockIdx.x * 128;
  int wave = tid >> 6, lane = tid & 63;
  int lrow = lane & 15, quad = lane >> 4;
  int k0 = quad * 8;

  f32x4 acc[2][8];
#pragma unroll
  for (int a = 0; a < 2; ++a)
#pragma unroll
    for (int b = 0; b < 8; ++b) acc[a][b] = (f32x4){0.f, 0.f, 0.f, 0.f};

  int r_st = tid >> 1;                // 0..127 staging row/col
  int hh = (tid & 1) * 16;            // 16-bf16 half
  int grow_st = rowBase + r_st;
  bool aval = grow_st < M;
  const int4 zero4 = {0, 0, 0, 0};

  for (int kc = 0; kc < 20; ++kc) {
    if (aval) {
      const unsigned short* ap = chunks[kc >> 2] + ((size_t)grow_st * WID + (kc & 3) * 32 + hh);
      *(int4*)(&As[r_st][hh]) = *(const int4*)ap;
      *(int4*)(&As[r_st][hh + 8]) = *(const int4*)(ap + 8);
    } else {
      *(int4*)(&As[r_st][hh]) = zero4;
      *(int4*)(&As[r_st][hh + 8]) = zero4;
    }
    {
      const unsigned short* bp = Wt + ((size_t)r_st * 640 + kc * 32 + hh);
      *(int4*)(&Bs[r_st][hh]) = *(const int4*)bp;
      *(int4*)(&Bs[r_st][hh + 8]) = *(const int4*)(bp + 8);
    }
    __syncthreads();

    bf16x8 a0 = *(bf16x8*)(&As[wave * 32 + lrow][k0]);
    bf16x8 a1 = *(bf16x8*)(&As[wave * 32 + 16 + lrow][k0]);
#pragma unroll
    for (int ct = 0; ct < 8; ++ct) {
      bf16x8 b = *(bf16x8*)(&Bs[ct * 16 + lrow][k0]);
      acc[0][ct] = __builtin_amdgcn_mfma_f32_16x16x32_bf16(a0, b, acc[0][ct], 0, 0, 0);
      acc[1][ct] = __builtin_amdgcn_mfma_f32_16x16x32_bf16(a1, b, acc[1][ct], 0, 0, 0);
    }
    __syncthreads();
  }

  // epilogue: C/D layout col=lane&15, row=quad*4+reg
#pragma unroll
  for (int rt = 0; rt < 2; ++rt) {
    int grow0 = rowBase + wave * 32 + rt * 16 + quad * 4;
#pragma unroll
    for (int ct = 0; ct < 8; ++ct) {
      int gcol = ct * 16 + lrow;
      float bv = bias[gcol];
#pragma unroll
      for (int reg = 0; reg < 4; ++reg) {
        int grow = grow0 + reg;
        if (grow < M) {
          float v = acc[rt][ct][reg] + bv;
          if (relu) v = fmaxf(v, 0.f);
          Hb[(size_t)grow * WID + gcol] = f2bf(v);
          if (Hf) Hf[(size_t)grow * WID + gcol] = v;
        }
      }
    }
  }
}

// ---------------- final Linear(128 -> 1) ----------------

__global__ __launch_bounds__(256) void linear_kernel(const float* __restrict__ h,
                                                     const float* __restrict__ w,
                                                     const float* __restrict__ b,
                                                     float* __restrict__ y, int n) {
  int node = blockIdx.x * 4 + (threadIdx.x >> 6);
  int lane = threadIdx.x & 63;
  if (node >= n) return;
  const float* hr = h + (size_t)node * WID;
  float v = hr[lane] * w[lane] + hr[lane + 64] * w[lane + 64];
#pragma unroll
  for (int off = 32; off > 0; off >>= 1) v += __shfl_down(v, off, 64);
  if (lane == 0) y[node] = v + b[0];
}

// ---------------- host orchestration ----------------

extern "C" void kernel_launch(void* const* d_in, const int* in_sizes, int n_in,
                              void* d_out, int out_size, void* d_ws, size_t ws_size,
                              hipStream_t stream) {
  const float* x = (const float*)d_in[0];
  const int* ei = (const int*)d_in[1];          // int32 per harness contract
  const float* conv_w = (const float*)d_in[2];  // [6][5][128][128]
  const float* conv_b = (const float*)d_in[3];  // [6][128]
  const float* lin_w = (const float*)d_in[4];   // [128]
  const float* lin_b = (const float*)d_in[5];   // [1]

  const int N = NN, E = NE, C = WID, L = 6;

  char* ws = (char*)d_ws;
  size_t off = 0;
  auto alloc = [&](size_t bytes) -> void* {
    void* p = ws + off;
    off = (off + bytes + 255) & ~(size_t)255;
    return p;
  };
  int* deg = (int*)alloc((size_t)N * 4);
  float* dinv = (float*)alloc((size_t)N * 4);
  int* row_start = (int*)alloc((size_t)(N + 1) * 4);
  int* fill_ptr = (int*)alloc((size_t)N * 4);
  int2* csr = (int2*)alloc((size_t)E * 8);
  float* H = (float*)alloc((size_t)N * C * 4);                     // fp32 final layer out
  unsigned short* Xbf = (unsigned short*)alloc((size_t)N * C * 2); // bf16 x
  unsigned short* Hb0 = (unsigned short*)alloc((size_t)N * C * 2);
  unsigned short* Hb1 = (unsigned short*)alloc((size_t)N * C * 2);
  unsigned short* T1b = (unsigned short*)alloc((size_t)N * C * 2);
  unsigned short* T2b = (unsigned short*)alloc((size_t)N * C * 2);
  unsigned short* T3b = (unsigned short*)alloc((size_t)N * C * 2);
  unsigned short* T4b = (unsigned short*)alloc((size_t)N * C * 2);
  unsigned short* Wt = (unsigned short*)alloc((size_t)L * C * 640 * 2);

  // preprocessing
  hipMemsetAsync(deg, 0, (size_t)N * 4, stream);
  degree_kernel<<<(E + 255) / 256, 256, 0, stream>>>(ei, deg, E);
  dinv_kernel<<<(N + 255) / 256, 256, 0, stream>>>(deg, dinv, N);
  scan_kernel<<<1, 1024, 0, stream>>>(deg, row_start, fill_ptr, N);
  fill_kernel<<<(E + 255) / 256, 256, 0, stream>>>(ei, dinv, fill_ptr, csr, E);
  cvt_x_kernel<<<(N * C + 255) / 256, 256, 0, stream>>>(x, Xbf, N * C);
  cvt_w_kernel<<<(L * C * 640 + 255) / 256, 256, 0, stream>>>(conv_w, Wt, L * C * 640);

  const int pg = (N + 7) / 8;        // prop grid
  const int gg = (N + 127) / 128;    // gemm grid

  for (int l = 0; l < L; ++l) {
    const unsigned short* T0 = (l == 0) ? Xbf : ((l & 1) ? Hb0 : Hb1);
    unsigned short* Hb = (l & 1) ? Hb1 : Hb0;
    float* Hf = (l == L - 1) ? H : nullptr;

    // T1 = L T0
    prop_kernel<<<pg, 256, 0, stream>>>(T1b, T0, nullptr, 1.0f, row_start, csr, N);
    // T2 = 2 L T1 - T0
    prop_kernel<<<pg, 256, 0, stream>>>(T2b, T1b, T0, 2.0f, row_start, csr, N);
    // T3 = 2 L T2 - T1
    prop_kernel<<<pg, 256, 0, stream>>>(T3b, T2b, T1b, 2.0f, row_start, csr, N);
    // T4 = 2 L T3 - T2
    prop_kernel<<<pg, 256, 0, stream>>>(T4b, T3b, T2b, 2.0f, row_start, csr, N);
    // fused GEMM over K=640 + bias (+ReLU) -> bf16 Hb (+ fp32 H on final layer)
    cheb_gemm<<<gg, 256, 0, stream>>>(T0, T1b, T2b, T3b, T4b,
                                      Wt + (size_t)l * C * 640, conv_b + (size_t)l * C,
                                      Hb, Hf, N, (l < L - 1) ? 1 : 0);
  }

  linear_kernel<<<(N + 3) / 4, 256, 0, stream>>>(H, lin_w, lin_b, (float*)d_out, N);
}